// Round 1
// baseline (1404.916 us; speedup 1.0000x reference)
//
#include <hip/hip_runtime.h>
#include <hip/hip_bf16.h>

// HisRepItself: DCT-attention + 12-block GCN, batch=128, nodes=66, feat=256.
// Round 1: full f32 implementation, correctness-first.
//
// Workspace layout (floats):
//   dct   @ 0        (400)
//   kc1   @ 512      (128*35*256)  [b][t][o]   (conv K stage 1, relu'd)
//   key   @ 1147392  (128*31*256)  [b][v][o]
//   qc1   @ 2163200  (128*5*256)
//   q     @ 2327040  (128*256)
//   att   @ 2359808  (128*32)
//   x     @ 2363904  (128*66*20)
//   y     @ 2532864  (128*66*256)
//   t     @ 4695552  (128*66*256)
//   w1t   @ 6858240  (396*256)   transposed conv weights (f32)
//   w2t   @ 6959616  (1280*256)
//   wq1t  @ 7287296  (396*256)
//   wq2t  @ 7388672  (1280*256)
//   t2    @ 7716352  (8448*20)
//   xo    @ 7885312  (8448*20)
//   h     @ 512      (overlays kc1/key -- dead after x is built)
// total 8054272 floats = 32.2 MB

#define BNI 0.9999950000374995f

__global__ __launch_bounds__(512) void k_init_dct(float* dct){
  int t = threadIdx.x;
  if (t < 400){
    int k = t / 20, i = t % 20;
    double w = (k == 0) ? sqrt(1.0/20.0) : sqrt(2.0/20.0);
    dct[t] = (float)(w * cos(3.14159265358979323846 * (i + 0.5) * k / 20.0));
  }
}

// out[k*256+o] = in[o*K+k]
__global__ __launch_bounds__(256) void k_wtrans(const float* __restrict__ in,
    float* __restrict__ out, int K, int total){
  int idx = blockIdx.x*256 + threadIdx.x;
  if (idx < total){
    int o = idx / K, k = idx % K;
    out[k*256 + o] = in[idx];
  }
}

// conv1 (KH=6): out[(b*nt_out+t)*256+o] = relu(sum_{c,h} src[b, t_off+t+h, c]*1e-3 * wt[(c*6+h)*256+o])
template<int TSPLIT, int NT_IN>
__global__ __launch_bounds__(256) void k_conv1(const float* __restrict__ src,
    const float* __restrict__ wt, float* __restrict__ out, int t_off, int nt_out){
  int b = blockIdx.x;
  int t0 = blockIdx.y * TSPLIT;
  int tcnt = min(TSPLIT, nt_out - t0);
  int o = threadIdx.x;
  __shared__ float srcs[66*NT_IN + 8];
  for (int idx = threadIdx.x; idx < 66*NT_IN; idx += 256){
    int c = idx / NT_IN, tt = idx % NT_IN;
    srcs[idx] = src[(b*50 + t_off + tt)*66 + c] * 1e-3f;
  }
  __syncthreads();
  float acc[TSPLIT];
  #pragma unroll
  for (int t = 0; t < TSPLIT; t++) acc[t] = 0.f;
  for (int c = 0; c < 66; c++){
    float r[TSPLIT + 5];
    #pragma unroll
    for (int j = 0; j < TSPLIT + 5; j++) r[j] = srcs[c*NT_IN + t0 + j];
    #pragma unroll
    for (int h = 0; h < 6; h++){
      float w = wt[(c*6 + h)*256 + o];
      #pragma unroll
      for (int t = 0; t < TSPLIT; t++) acc[t] += w * r[t + h];
    }
  }
  for (int t = 0; t < tcnt; t++)
    out[(b*nt_out + t0 + t)*256 + o] = fmaxf(acc[t], 0.f);
}

// conv2 (KH=5): out[(b*nt_out+t)*256+o] = relu(sum_{c<256,h<5} in[(b*NT_IN+t+h)*256+c] * wt[(c*5+h)*256+o])
template<int TSPLIT, int NT_IN>
__global__ __launch_bounds__(256) void k_conv2(const float* __restrict__ in,
    const float* __restrict__ wt, float* __restrict__ out, int nt_out){
  int b = blockIdx.x;
  int t0 = blockIdx.y * TSPLIT;
  int tcnt = min(TSPLIT, nt_out - t0);
  int o = threadIdx.x;
  __shared__ float ins[256*(NT_IN + 1) + 8];
  for (int idx = threadIdx.x; idx < 256*NT_IN; idx += 256){
    int tt = idx >> 8, c = idx & 255;
    ins[c*(NT_IN + 1) + tt] = in[(b*NT_IN + tt)*256 + c];
  }
  __syncthreads();
  float acc[TSPLIT];
  #pragma unroll
  for (int t = 0; t < TSPLIT; t++) acc[t] = 0.f;
  for (int c = 0; c < 256; c++){
    float r[TSPLIT + 4];
    #pragma unroll
    for (int j = 0; j < TSPLIT + 4; j++) r[j] = ins[c*(NT_IN + 1) + t0 + j];
    #pragma unroll
    for (int h = 0; h < 5; h++){
      float w = wt[(c*5 + h)*256 + o];
      #pragma unroll
      for (int t = 0; t < TSPLIT; t++) acc[t] += w * r[t + h];
    }
  }
  for (int t = 0; t < tcnt; t++)
    out[(b*nt_out + t0 + t)*256 + o] = fmaxf(acc[t], 0.f);
}

// att[b*32+v] = (q[b]·key[b,v] + 1e-15) / sum_v(...)
__global__ __launch_bounds__(64) void k_att(const float* __restrict__ q,
    const float* __restrict__ key, float* __restrict__ att){
  int b = blockIdx.x;
  int lane = threadIdx.x;
  float s = 0.f;
  if (lane < 31){
    const float* kr = key + (b*31 + lane)*256;
    const float* qr = q + b*256;
    for (int o = 0; o < 256; o++) s += qr[o] * kr[o];
    s += 1e-15f;
  }
  float tot = s;
  for (int off = 32; off; off >>= 1) tot += __shfl_down(tot, off);
  tot = __shfl(tot, 0);
  if (lane < 31) att[b*32 + lane] = s / tot;
}

// x[(b*66+f)*20 + k]    = sum_i dct[k,i] * src[b, idx2[i], f]          (k<10)
// x[(b*66+f)*20 + 10+k] = sum_i dct[k,i] * (sum_v att[v]*src[b,v+i,f]) (k<10)
__global__ __launch_bounds__(256) void k_build_x(const float* __restrict__ src,
    const float* __restrict__ att, const float* __restrict__ dct, float* __restrict__ x){
  int b = blockIdx.x;
  int tid = threadIdx.x;
  __shared__ float z[20*66];
  __shared__ float a[31];
  if (tid < 31) a[tid] = att[b*32 + tid];
  __syncthreads();
  for (int idx = tid; idx < 1320; idx += 256){
    int i = idx / 66, f = idx % 66;
    float s = 0.f;
    for (int v = 0; v < 31; v++) s += a[v] * src[(b*50 + v + i)*66 + f];
    z[idx] = s;
  }
  __syncthreads();
  for (int idx = tid; idx < 660; idx += 256){
    int f = idx / 10, k = idx % 10;
    float s1 = 0.f, s2 = 0.f;
    #pragma unroll
    for (int i = 0; i < 20; i++){
      float d = dct[k*20 + i];
      int tt = (i < 10) ? (40 + i) : 49;
      s1 += d * src[(b*50 + tt)*66 + f];
      s2 += d * z[i*66 + f];
    }
    x[(b*66 + f)*20 + k] = s1;
    x[(b*66 + f)*20 + 10 + k] = s2;
  }
}

// t[row,f] = sum_{k<20} x[row,k] * w[k,f]   (rows = 8448, f = 256)
__global__ __launch_bounds__(256) void k_gemm_k20(const float* __restrict__ x,
    const float* __restrict__ w, float* __restrict__ t){
  int row0 = blockIdx.x * 4;
  int f = threadIdx.x;
  for (int r = 0; r < 4; r++){
    int row = row0 + r;
    float acc = 0.f;
    #pragma unroll
    for (int k = 0; k < 20; k++) acc += x[row*20 + k] * w[k*256 + f];
    t[row*256 + f] = acc;
  }
}

// C[8448x256] = A[8448x256] * B[256x256], tile 32x64, micro 2x4
__global__ __launch_bounds__(256) void k_gemm(const float* __restrict__ A,
    const float* __restrict__ B, float* __restrict__ C){
  __shared__ __align__(16) float As[16][36];
  __shared__ __align__(16) float Bs[16][68];
  int rowbase = blockIdx.x * 32, colbase = blockIdx.y * 64;
  int tid = threadIdx.x;
  int tx = tid & 15, ty = tid >> 4;
  float acc[2][4] = {{0.f}};
  for (int k0 = 0; k0 < 256; k0 += 16){
    #pragma unroll
    for (int l = 0; l < 2; l++){
      int e = tid + l*256; int i = e >> 4, k = e & 15;
      As[k][i] = A[(rowbase + i)*256 + k0 + k];
    }
    #pragma unroll
    for (int l = 0; l < 4; l++){
      int e = tid + l*256; int k = e >> 6, j = e & 63;
      Bs[k][j] = B[(k0 + k)*256 + colbase + j];
    }
    __syncthreads();
    #pragma unroll
    for (int k = 0; k < 16; k++){
      float a0 = As[k][ty*2], a1 = As[k][ty*2 + 1];
      float4 b4 = *(const float4*)&Bs[k][tx*4];
      acc[0][0] += a0*b4.x; acc[0][1] += a0*b4.y; acc[0][2] += a0*b4.z; acc[0][3] += a0*b4.w;
      acc[1][0] += a1*b4.x; acc[1][1] += a1*b4.y; acc[1][2] += a1*b4.z; acc[1][3] += a1*b4.w;
    }
    __syncthreads();
  }
  #pragma unroll
  for (int r = 0; r < 2; r++){
    float4 ov = {acc[r][0], acc[r][1], acc[r][2], acc[r][3]};
    *(float4*)&C[(rowbase + ty*2 + r)*256 + colbase + tx*4] = ov;
  }
}

// out[b,n,f] = [tanh]( (sum_m A[n,m]*t[b,m,f] + bias[f]) [*g*BNI + be] ) [+ res]
__global__ __launch_bounds__(272) void k_amult(const float* __restrict__ t,
    const float* __restrict__ A, const float* __restrict__ bias,
    const float* __restrict__ g, const float* __restrict__ be,
    const float* __restrict__ res, float* __restrict__ out, int do_tanh){
  int b = blockIdx.x;
  int quad = blockIdx.y;           // 64-wide f block
  int tid = threadIdx.x;           // 272 = 17 nq * 16 fq
  __shared__ __align__(16) float ts[66*64];
  __shared__ __align__(16) float At[66*68];
  for (int idx = tid; idx < 66*64; idx += 272){
    int m = idx >> 6, f = idx & 63;
    ts[idx] = t[(b*66 + m)*256 + quad*64 + f];
  }
  for (int idx = tid; idx < 66*68; idx += 272){
    int m = idx / 68, n = idx % 68;
    At[idx] = (n < 66) ? A[n*66 + m] : 0.f;
  }
  __syncthreads();
  int nq = tid / 16, fq = tid & 15;
  const float4* ts4 = (const float4*)ts;
  const float4* At4 = (const float4*)At;
  float acc[4][4] = {{0.f}};
  for (int m = 0; m < 66; m++){
    float4 tv = ts4[m*16 + fq];
    float4 av = At4[m*17 + nq];
    acc[0][0] += av.x*tv.x; acc[0][1] += av.x*tv.y; acc[0][2] += av.x*tv.z; acc[0][3] += av.x*tv.w;
    acc[1][0] += av.y*tv.x; acc[1][1] += av.y*tv.y; acc[1][2] += av.y*tv.z; acc[1][3] += av.y*tv.w;
    acc[2][0] += av.z*tv.x; acc[2][1] += av.z*tv.y; acc[2][2] += av.z*tv.z; acc[2][3] += av.z*tv.w;
    acc[3][0] += av.w*tv.x; acc[3][1] += av.w*tv.y; acc[3][2] += av.w*tv.z; acc[3][3] += av.w*tv.w;
  }
  int f0 = quad*64 + fq*4;
  #pragma unroll
  for (int r = 0; r < 4; r++){
    int n = nq*4 + r;
    if (n >= 66) break;
    int row = b*66 + n;
    int bni = n*256 + f0;
    float v0 = acc[r][0] + bias[f0 + 0];
    float v1 = acc[r][1] + bias[f0 + 1];
    float v2 = acc[r][2] + bias[f0 + 2];
    float v3 = acc[r][3] + bias[f0 + 3];
    if (g){
      float4 gv = *(const float4*)&g[bni];
      float4 bv = *(const float4*)&be[bni];
      v0 = v0*gv.x*BNI + bv.x; v1 = v1*gv.y*BNI + bv.y;
      v2 = v2*gv.z*BNI + bv.z; v3 = v3*gv.w*BNI + bv.w;
    }
    if (do_tanh){ v0 = tanhf(v0); v1 = tanhf(v1); v2 = tanhf(v2); v3 = tanhf(v3); }
    if (res){
      float4 rv = *(const float4*)&res[row*256 + f0];
      v0 += rv.x; v1 += rv.y; v2 += rv.z; v3 += rv.w;
    }
    float4 ov = {v0, v1, v2, v3};
    *(float4*)&out[row*256 + f0] = ov;
  }
}

// t2[row,f] = sum_{k<256} y[row,k] * w[k*20+f]   (f<20)
__global__ __launch_bounds__(320) void k_gemm_n20(const float* __restrict__ y,
    const float* __restrict__ w, float* __restrict__ t2){
  __shared__ float ws[256*20];
  __shared__ float ys[16*256];
  int tid = threadIdx.x;
  int row0 = blockIdx.x * 16;
  for (int idx = tid; idx < 5120; idx += 320) ws[idx] = w[idx];
  for (int idx = tid; idx < 4096; idx += 320) ys[idx] = y[row0*256 + idx];
  __syncthreads();
  int s = tid / 20, f = tid % 20;
  float acc = 0.f;
  for (int k = 0; k < 256; k++) acc += ys[s*256 + k] * ws[k*20 + f];
  t2[(row0 + s)*20 + f] = acc;
}

// xo[b,n,f] = sum_m A[n,m]*t2[b,m,f] + bias[f] + x[b,n,f]   (f<20)
__global__ __launch_bounds__(512) void k_amult20(const float* __restrict__ t2,
    const float* __restrict__ A, const float* __restrict__ bias,
    const float* __restrict__ x, float* __restrict__ xo){
  int b = blockIdx.x;
  int tid = threadIdx.x;
  __shared__ float ts[66*20];
  for (int idx = tid; idx < 1320; idx += 512) ts[idx] = t2[b*1320 + idx];
  __syncthreads();
  for (int idx = tid; idx < 1320; idx += 512){
    int n = idx / 20, f = idx % 20;
    float acc = bias[f];
    for (int m = 0; m < 66; m++) acc += A[n*66 + m] * ts[m*20 + f];
    xo[b*1320 + idx] = acc + x[b*1320 + idx];
  }
}

// out[b,r,f] = sum_{k<10} dct[k*20+r] * xo[(b*66+f)*20+k]   (idct = dct^T)
__global__ __launch_bounds__(512) void k_out(const float* __restrict__ xo,
    const float* __restrict__ dct, float* __restrict__ out){
  int b = blockIdx.x;
  int tid = threadIdx.x;
  __shared__ float xs[66*20];
  for (int idx = tid; idx < 1320; idx += 512) xs[idx] = xo[b*1320 + idx];
  __syncthreads();
  for (int idx = tid; idx < 1320; idx += 512){
    int r = idx / 66, f = idx % 66;
    float s = 0.f;
    #pragma unroll
    for (int k = 0; k < 10; k++) s += dct[k*20 + r] * xs[f*20 + k];
    out[(b*20 + r)*66 + f] = s;
  }
}

extern "C" void kernel_launch(void* const* d_in, const int* in_sizes, int n_in,
                              void* d_out, int out_size, void* d_ws, size_t ws_size,
                              hipStream_t stream) {
  const float* src      = (const float*)d_in[0];
  const float* convQ_w1 = (const float*)d_in[1];
  const float* convQ_w2 = (const float*)d_in[2];
  const float* convK_w1 = (const float*)d_in[3];
  const float* convK_w2 = (const float*)d_in[4];
  const float* gc1_w    = (const float*)d_in[5];
  const float* gc1_att  = (const float*)d_in[6];
  const float* gc1_b    = (const float*)d_in[7];
  const float* bn1_g    = (const float*)d_in[8];
  const float* bn1_b    = (const float*)d_in[9];
  const float* gcb_w1   = (const float*)d_in[10];
  const float* gcb_att1 = (const float*)d_in[11];
  const float* gcb_b1   = (const float*)d_in[12];
  const float* gcb_bn1g = (const float*)d_in[13];
  const float* gcb_bn1b = (const float*)d_in[14];
  const float* gcb_w2   = (const float*)d_in[15];
  const float* gcb_att2 = (const float*)d_in[16];
  const float* gcb_b2   = (const float*)d_in[17];
  const float* gcb_bn2g = (const float*)d_in[18];
  const float* gcb_bn2b = (const float*)d_in[19];
  const float* gc7_w    = (const float*)d_in[20];
  const float* gc7_att  = (const float*)d_in[21];
  const float* gc7_b    = (const float*)d_in[22];
  float* out = (float*)d_out;

  float* ws  = (float*)d_ws;
  float* dct = ws + 0;
  float* kc1 = ws + 512;
  float* key = ws + 1147392;
  float* qc1 = ws + 2163200;
  float* q   = ws + 2327040;
  float* att = ws + 2359808;
  float* x   = ws + 2363904;
  float* y   = ws + 2532864;
  float* t   = ws + 4695552;
  float* w1t = ws + 6858240;
  float* w2t = ws + 6959616;
  float* wq1t= ws + 7287296;
  float* wq2t= ws + 7388672;
  float* t2  = ws + 7716352;
  float* xo  = ws + 7885312;
  float* h   = ws + 512;   // overlay (kc1/key dead by the time h is used)

  k_init_dct<<<1, 512, 0, stream>>>(dct);
  k_wtrans<<<(101376+255)/256, 256, 0, stream>>>(convK_w1, w1t, 396, 101376);
  k_wtrans<<<(327680+255)/256, 256, 0, stream>>>(convK_w2, w2t, 1280, 327680);
  k_wtrans<<<(101376+255)/256, 256, 0, stream>>>(convQ_w1, wq1t, 396, 101376);
  k_wtrans<<<(327680+255)/256, 256, 0, stream>>>(convQ_w2, wq2t, 1280, 327680);

  k_conv1<18,40><<<dim3(128,2), 256, 0, stream>>>(src, w1t, kc1, 0, 35);
  k_conv2<16,35><<<dim3(128,2), 256, 0, stream>>>(kc1, w2t, key, 31);
  k_conv1<5,10><<<dim3(128,1), 256, 0, stream>>>(src, wq1t, qc1, 40, 5);
  k_conv2<1,5><<<dim3(128,1), 256, 0, stream>>>(qc1, wq2t, q, 1);

  k_att<<<128, 64, 0, stream>>>(q, key, att);
  k_build_x<<<128, 256, 0, stream>>>(src, att, dct, x);

  k_gemm_k20<<<2112, 256, 0, stream>>>(x, gc1_w, t);
  k_amult<<<dim3(128,4), 272, 0, stream>>>(t, gc1_att, gc1_b, bn1_g, bn1_b, nullptr, y, 1);

  for (int i = 0; i < 12; i++){
    k_gemm<<<dim3(264,4), 256, 0, stream>>>(y, gcb_w1 + i*65536, t);
    k_amult<<<dim3(128,4), 272, 0, stream>>>(t, gcb_att1 + i*4356, gcb_b1 + i*256,
        gcb_bn1g + i*16896, gcb_bn1b + i*16896, nullptr, h, 1);
    k_gemm<<<dim3(264,4), 256, 0, stream>>>(h, gcb_w2 + i*65536, t);
    k_amult<<<dim3(128,4), 272, 0, stream>>>(t, gcb_att2 + i*4356, gcb_b2 + i*256,
        gcb_bn2g + i*16896, gcb_bn2b + i*16896, y, y, 1);
  }

  k_gemm_n20<<<528, 320, 0, stream>>>(y, gc7_w, t2);
  k_amult20<<<128, 512, 0, stream>>>(t2, gc7_att, gc7_b, x, xo);
  k_out<<<128, 512, 0, stream>>>(xo, dct, out);
}

// Round 2
// 742.511 us; speedup vs baseline: 1.8921x; 1.8921x over previous
//
#include <hip/hip_runtime.h>
#include <hip/hip_bf16.h>

// HisRepItself round 2: bf16-MFMA everywhere matmul-shaped.
//  - k_conv1/k_conv2: im2col MFMA GEMMs, key+query fused along N (weights concat).
//  - k_layer<KSTEPS>: fused (in_bf @ W) -> LDS -> (A @ t) -> bias/BN/tanh[/res],
//    dual f32+bf16 outputs (residual stays f32).
//  - f32 tail (att, build_x, gc7) kept from proven round-1 code.
//
// Workspace (f32 units), total 7,906,816 floats = 31.6 MB (< proven 32.2):
//   dct 0(400) | x 512(168960) | y 169472(2162688) | y_bf 2332160(eq 1310720)
//   U = 3642880 (4263936):
//     early: w1T U+0 | w2T U+131072 | kc1q U+458752 | key U+1114112 |
//            q U+2129920 | att U+2162688
//     mid:   x_bf U+1114112 (overlays dead key)
//     late:  wgT U+0 | gc1wT U+786432 | h U+790528 | h_bf U+2953216
//     tail:  t2 U+0 | xo U+168960 (overlay dead wgT)

typedef __attribute__((ext_vector_type(8))) short short8;
typedef __attribute__((ext_vector_type(4))) short short4v;
typedef __attribute__((ext_vector_type(4))) float float4v;

#define BNI 0.9999950000374995f

__device__ inline short f2bf(float x){
  unsigned u = __float_as_uint(x);
  unsigned r = (u + 0x7fff + ((u >> 16) & 1)) >> 16;
  return (short)r;
}

__global__ __launch_bounds__(512) void k_init_dct(float* dct){
  int t = threadIdx.x;
  if (t < 400){
    int k = t / 20, i = t % 20;
    double w = (k == 0) ? sqrt(1.0/20.0) : sqrt(2.0/20.0);
    dct[t] = (float)(w * cos(3.14159265358979323846 * (i + 0.5) * k / 20.0));
  }
}

// ---------------- weight prep ----------------
// w1T[512][512]: f<256 key, f>=256 query; k = h*66+c (k<396, else 0)
__global__ __launch_bounds__(256) void k_wconv1(const float* __restrict__ wK,
    const float* __restrict__ wQ, short* __restrict__ w1T){
  int idx = blockIdx.x*256 + threadIdx.x;
  if (idx >= 512*512) return;
  int f = idx >> 9, k = idx & 511;
  float v = 0.f;
  if (k < 396){
    int h = k / 66, c = k - h*66;
    const float* s = (f < 256) ? wK : wQ;
    v = s[((f & 255)*66 + c)*6 + h];
  }
  w1T[idx] = f2bf(v);
}

// w2T[512][1280]: k = h*256+c
__global__ __launch_bounds__(256) void k_wconv2(const float* __restrict__ wK,
    const float* __restrict__ wQ, short* __restrict__ w2T){
  int idx = blockIdx.x*256 + threadIdx.x;
  if (idx >= 512*1280) return;
  int f = idx / 1280, k = idx - f*1280;
  int h = k >> 8, c = k & 255;
  const float* s = (f < 256) ? wK : wQ;
  w2T[idx] = f2bf(s[((f & 255)*256 + c)*5 + h]);
}

// wgT[24][256 f][256 k] from gcb_w1 (l<12) / gcb_w2
__global__ __launch_bounds__(256) void k_wgcn(const float* __restrict__ w1,
    const float* __restrict__ w2, short* __restrict__ wgT){
  int idx = blockIdx.x*256 + threadIdx.x;
  if (idx >= 24*65536) return;
  int l = idx >> 16, r = idx & 65535;
  int f = r >> 8, k = r & 255;
  const float* s = (l < 12) ? (w1 + l*65536) : (w2 + (l-12)*65536);
  wgT[idx] = f2bf(s[k*256 + f]);
}

// gc1wT[256 f][32 k] (k<20 real)
__global__ __launch_bounds__(256) void k_wgc1(const float* __restrict__ w,
    short* __restrict__ wT){
  int idx = blockIdx.x*256 + threadIdx.x;
  if (idx >= 8192) return;
  int f = idx >> 5, k = idx & 31;
  wT[idx] = f2bf(k < 20 ? w[k*256 + f] : 0.f);
}

// ---------------- conv1 (key rows 0..34, query rows 35..39) ----------------
__global__ __launch_bounds__(256) void k_conv1(const float* __restrict__ src,
    const short* __restrict__ w1T, short* __restrict__ kc1q){
  int b = blockIdx.x, ns = blockIdx.y;
  int f0 = ns*128;
  __shared__ short Aim[48*424];
  __shared__ short Wt[128*72];
  int tid = threadIdx.x;
  for (int idx = tid; idx < 48*424; idx += 256){
    int t = idx / 424, kk = idx - t*424;
    float v = 0.f;
    if (kk < 396 && t < 40){
      int h = kk / 66, c = kk - h*66;
      int row = t + h + ((t >= 35) ? 5 : 0);
      v = src[(b*50 + row)*66 + c] * 1e-3f;
    }
    Aim[idx] = f2bf(v);
  }
  int w = tid >> 6, lane = tid & 63, fl = lane & 15, g = lane >> 4;
  float4v acc[3][2];
  #pragma unroll
  for (int i=0;i<3;i++) for (int n=0;n<2;n++) acc[i][n] = (float4v){0.f,0.f,0.f,0.f};
  for (int kt = 0; kt < 416; kt += 64){
    __syncthreads();
    for (int ch = tid; ch < 128*8; ch += 256){
      int r = ch >> 3, kq = ch & 7;
      *(short8*)&Wt[r*72 + kq*8] = *(const short8*)&w1T[(f0 + r)*512 + kt + kq*8];
    }
    __syncthreads();
    int nst = (416 - kt >= 64) ? 2 : 1;
    for (int s = 0; s < nst; s++){
      int k0 = s*32;
      short8 bfr0 = *(const short8*)&Wt[(w*32 + fl)*72 + k0 + g*8];
      short8 bfr1 = *(const short8*)&Wt[(w*32 + 16 + fl)*72 + k0 + g*8];
      #pragma unroll
      for (int i=0;i<3;i++){
        short8 afr = *(const short8*)&Aim[(i*16 + fl)*424 + kt + k0 + g*8];
        acc[i][0] = __builtin_amdgcn_mfma_f32_16x16x32_bf16(afr, bfr0, acc[i][0], 0,0,0);
        acc[i][1] = __builtin_amdgcn_mfma_f32_16x16x32_bf16(afr, bfr1, acc[i][1], 0,0,0);
      }
    }
  }
  #pragma unroll
  for (int i=0;i<3;i++) for (int n=0;n<2;n++) for (int j=0;j<4;j++){
    int t = i*16 + g*4 + j;
    int f = f0 + w*32 + n*16 + fl;
    float v = fmaxf(acc[i][n][j], 0.f);
    if (t < 35 && f < 256) kc1q[(b*40 + t)*256 + f] = f2bf(v);
    else if (t >= 35 && t < 40 && f >= 256) kc1q[(b*40 + t)*256 + (f - 256)] = f2bf(v);
  }
}

// ---------------- conv2 (key rows 0..30, query row 31) ----------------
__global__ __launch_bounds__(256) void k_conv2(const short* __restrict__ kc1q,
    const short* __restrict__ w2T, float* __restrict__ key, float* __restrict__ q){
  int b = blockIdx.x, ns = blockIdx.y;
  int f0 = ns*128;
  __shared__ short kcs[40*256];
  __shared__ short Wt[128*136];
  char* kcb = (char*)kcs;
  int tid = threadIdx.x;
  for (int ch = tid; ch < 1280; ch += 256){
    int r = ch >> 5, kq = ch & 31;
    unsigned byte = (unsigned)(r*512 + kq*16) ^ (unsigned)((r & 7) << 4);
    *(short8*)(kcb + byte) = *(const short8*)&kc1q[(b*40 + r)*256 + kq*8];
  }
  int w = tid >> 6, lane = tid & 63, fl = lane & 15, g = lane >> 4;
  float4v acc[2][2];
  #pragma unroll
  for (int i=0;i<2;i++) for (int n=0;n<2;n++) acc[i][n] = (float4v){0.f,0.f,0.f,0.f};
  for (int kt = 0; kt < 1280; kt += 128){
    __syncthreads();
    for (int ch = tid; ch < 128*16; ch += 256){
      int r = ch >> 4, kq = ch & 15;
      *(short8*)&Wt[r*136 + kq*8] = *(const short8*)&w2T[(f0 + r)*1280 + kt + kq*8];
    }
    __syncthreads();
    #pragma unroll
    for (int s = 0; s < 4; s++){
      int k = kt + s*32;
      int h = k >> 8, cb = k & 255;
      short8 bfr0 = *(const short8*)&Wt[(w*32 + fl)*136 + s*32 + g*8];
      short8 bfr1 = *(const short8*)&Wt[(w*32 + 16 + fl)*136 + s*32 + g*8];
      #pragma unroll
      for (int i=0;i<2;i++){
        int t = i*16 + fl;
        int row = t + h + ((t == 31) ? 4 : 0);
        unsigned byte = (unsigned)(row*512 + (cb + g*8)*2) ^ (unsigned)((row & 7) << 4);
        short8 afr = *(const short8*)(kcb + byte);
        acc[i][0] = __builtin_amdgcn_mfma_f32_16x16x32_bf16(afr, bfr0, acc[i][0], 0,0,0);
        acc[i][1] = __builtin_amdgcn_mfma_f32_16x16x32_bf16(afr, bfr1, acc[i][1], 0,0,0);
      }
    }
  }
  #pragma unroll
  for (int i=0;i<2;i++) for (int n=0;n<2;n++) for (int j=0;j<4;j++){
    int t = i*16 + g*4 + j;
    int f = f0 + w*32 + n*16 + fl;
    float v = fmaxf(acc[i][n][j], 0.f);
    if (t < 31 && f < 256) key[(b*31 + t)*256 + f] = v;
    else if (t == 31 && f >= 256) q[b*256 + f - 256] = v;
  }
}

// ---------------- attention ----------------
__global__ __launch_bounds__(64) void k_att(const float* __restrict__ q,
    const float* __restrict__ key, float* __restrict__ att){
  int b = blockIdx.x;
  int lane = threadIdx.x;
  float s = 0.f;
  if (lane < 31){
    const float* kr = key + (b*31 + lane)*256;
    const float* qr = q + b*256;
    for (int o = 0; o < 256; o++) s += qr[o] * kr[o];
    s += 1e-15f;
  }
  float tot = s;
  for (int off = 32; off; off >>= 1) tot += __shfl_down(tot, off);
  tot = __shfl(tot, 0);
  if (lane < 31) att[b*32 + lane] = s / tot;
}

// ---------------- build x (f32 + bf16-padded [80][32]) ----------------
__global__ __launch_bounds__(256) void k_build_x(const float* __restrict__ src,
    const float* __restrict__ att, const float* __restrict__ dct,
    float* __restrict__ x, short* __restrict__ x_bf){
  int b = blockIdx.x;
  int tid = threadIdx.x;
  __shared__ float z[20*66];
  __shared__ float a[31];
  for (int i = tid; i < 2560; i += 256) x_bf[b*2560 + i] = 0;
  if (tid < 31) a[tid] = att[b*32 + tid];
  __syncthreads();
  for (int idx = tid; idx < 1320; idx += 256){
    int i = idx / 66, f = idx % 66;
    float s = 0.f;
    for (int v = 0; v < 31; v++) s += a[v] * src[(b*50 + v + i)*66 + f];
    z[idx] = s;
  }
  __syncthreads();
  for (int idx = tid; idx < 660; idx += 256){
    int f = idx / 10, k = idx % 10;
    float s1 = 0.f, s2 = 0.f;
    #pragma unroll
    for (int i = 0; i < 20; i++){
      float d = dct[k*20 + i];
      int tt = (i < 10) ? (40 + i) : 49;
      s1 += d * src[(b*50 + tt)*66 + f];
      s2 += d * z[i*66 + f];
    }
    x[(b*66 + f)*20 + k] = s1;
    x[(b*66 + f)*20 + 10 + k] = s2;
    x_bf[(b*80 + f)*32 + k] = f2bf(s1);
    x_bf[(b*80 + f)*32 + 10 + k] = f2bf(s2);
  }
}

// ---------------- fused GCN layer ----------------
// t = in_bf[b](80xK) @ W(Kx256 via wT[f][k]); o = tanh(bn(A@t + bias)) [+res]
template<int KSTEPS>
__global__ __launch_bounds__(256) void k_layer(const short* __restrict__ in_bf,
    const short* __restrict__ wT, const float* __restrict__ Af,
    const float* __restrict__ bias, const float* __restrict__ gg,
    const float* __restrict__ be, const float* __restrict__ res,
    float* __restrict__ out_f, short* __restrict__ out_bf){
  constexpr int K = KSTEPS*32;
  int b = blockIdx.x, ns = blockIdx.y;
  int f0 = ns*64;
  __shared__ short Wt[64*(K + 8)];
  __shared__ short Al[80*104];
  __shared__ short tT[64*104];
  int tid = threadIdx.x;
  for (int ch = tid; ch < 64*(K/8); ch += 256){
    int r = ch / (K/8), kq = ch % (K/8);
    *(short8*)&Wt[r*(K+8) + kq*8] = *(const short8*)&wT[(f0 + r)*K + kq*8];
  }
  int* Ai = (int*)Al;
  for (int i = tid; i < 80*104/2; i += 256) Ai[i] = 0;
  int* Ti = (int*)tT;
  for (int i = tid; i < 64*104/2; i += 256) Ti[i] = 0;
  __syncthreads();
  for (int i = tid; i < 4356; i += 256){
    int n = i / 66, m = i - n*66;
    Al[n*104 + m] = f2bf(Af[i]);
  }
  __syncthreads();
  int w = tid >> 6, lane = tid & 63, fl = lane & 15, g = lane >> 4;
  float4v acc[5];
  #pragma unroll
  for (int i=0;i<5;i++) acc[i] = (float4v){0.f,0.f,0.f,0.f};
  const short* abase = in_bf + (long)b*80*K;
  #pragma unroll
  for (int ks = 0; ks < KSTEPS; ks++){
    int k0 = ks*32;
    short8 bfr = *(const short8*)&Wt[(w*16 + fl)*(K+8) + k0 + g*8];
    #pragma unroll
    for (int i=0;i<5;i++){
      short8 afr = *(const short8*)&abase[(i*16 + fl)*K + k0 + g*8];
      acc[i] = __builtin_amdgcn_mfma_f32_16x16x32_bf16(afr, bfr, acc[i], 0,0,0);
    }
  }
  #pragma unroll
  for (int i=0;i<5;i++){
    short4v p;
    p[0] = f2bf(acc[i][0]); p[1] = f2bf(acc[i][1]);
    p[2] = f2bf(acc[i][2]); p[3] = f2bf(acc[i][3]);
    *(short4v*)&tT[(w*16 + fl)*104 + i*16 + g*4] = p;
  }
  __syncthreads();
  float4v acc2[5];
  #pragma unroll
  for (int i=0;i<5;i++) acc2[i] = (float4v){0.f,0.f,0.f,0.f};
  #pragma unroll
  for (int ks = 0; ks < 3; ks++){
    int k0 = ks*32;
    short8 bfr = *(const short8*)&tT[(w*16 + fl)*104 + k0 + g*8];
    #pragma unroll
    for (int i=0;i<5;i++){
      short8 afr = *(const short8*)&Al[(i*16 + fl)*104 + k0 + g*8];
      acc2[i] = __builtin_amdgcn_mfma_f32_16x16x32_bf16(afr, bfr, acc2[i], 0,0,0);
    }
  }
  int f = f0 + w*16 + fl;
  #pragma unroll
  for (int i=0;i<5;i++){
    #pragma unroll
    for (int j=0;j<4;j++){
      int n = i*16 + g*4 + j;
      long obf = ((long)b*80 + n)*256 + f;
      if (n < 66){
        float v = acc2[i][j] + bias[f];
        int bi = n*256 + f;
        v = v * (gg[bi] * BNI) + be[bi];
        v = tanhf(v);
        long o = ((long)b*66 + n)*256 + f;
        if (res) v += res[o];
        out_f[o] = v;
        out_bf[obf] = f2bf(v);
      } else {
        out_bf[obf] = 0;
      }
    }
  }
}

// ---------------- gc7 tail (f32, proven) ----------------
__global__ __launch_bounds__(320) void k_gemm_n20(const float* __restrict__ y,
    const float* __restrict__ w, float* __restrict__ t2){
  __shared__ float wsd[256*20];
  __shared__ float ys[16*256];
  int tid = threadIdx.x;
  int row0 = blockIdx.x * 16;
  for (int idx = tid; idx < 5120; idx += 320) wsd[idx] = w[idx];
  for (int idx = tid; idx < 4096; idx += 320) ys[idx] = y[row0*256 + idx];
  __syncthreads();
  int s = tid / 20, f = tid % 20;
  float acc = 0.f;
  for (int k = 0; k < 256; k++) acc += ys[s*256 + k] * wsd[k*20 + f];
  t2[(row0 + s)*20 + f] = acc;
}

__global__ __launch_bounds__(512) void k_amult20(const float* __restrict__ t2,
    const float* __restrict__ A, const float* __restrict__ bias,
    const float* __restrict__ x, float* __restrict__ xo){
  int b = blockIdx.x;
  int tid = threadIdx.x;
  __shared__ float ts[66*20];
  for (int idx = tid; idx < 1320; idx += 512) ts[idx] = t2[b*1320 + idx];
  __syncthreads();
  for (int idx = tid; idx < 1320; idx += 512){
    int n = idx / 20, f = idx % 20;
    float acc = bias[f];
    for (int m = 0; m < 66; m++) acc += A[n*66 + m] * ts[m*20 + f];
    xo[b*1320 + idx] = acc + x[b*1320 + idx];
  }
}

__global__ __launch_bounds__(512) void k_out(const float* __restrict__ xo,
    const float* __restrict__ dct, float* __restrict__ out){
  int b = blockIdx.x;
  int tid = threadIdx.x;
  __shared__ float xs[66*20];
  for (int idx = tid; idx < 1320; idx += 512) xs[idx] = xo[b*1320 + idx];
  __syncthreads();
  for (int idx = tid; idx < 1320; idx += 512){
    int r = idx / 66, f = idx % 66;
    float s = 0.f;
    #pragma unroll
    for (int k = 0; k < 10; k++) s += dct[k*20 + r] * xs[f*20 + k];
    out[(b*20 + r)*66 + f] = s;
  }
}

extern "C" void kernel_launch(void* const* d_in, const int* in_sizes, int n_in,
                              void* d_out, int out_size, void* d_ws, size_t ws_size,
                              hipStream_t stream) {
  const float* src      = (const float*)d_in[0];
  const float* convQ_w1 = (const float*)d_in[1];
  const float* convQ_w2 = (const float*)d_in[2];
  const float* convK_w1 = (const float*)d_in[3];
  const float* convK_w2 = (const float*)d_in[4];
  const float* gc1_w    = (const float*)d_in[5];
  const float* gc1_att  = (const float*)d_in[6];
  const float* gc1_b    = (const float*)d_in[7];
  const float* bn1_g    = (const float*)d_in[8];
  const float* bn1_b    = (const float*)d_in[9];
  const float* gcb_w1   = (const float*)d_in[10];
  const float* gcb_att1 = (const float*)d_in[11];
  const float* gcb_b1   = (const float*)d_in[12];
  const float* gcb_bn1g = (const float*)d_in[13];
  const float* gcb_bn1b = (const float*)d_in[14];
  const float* gcb_w2   = (const float*)d_in[15];
  const float* gcb_att2 = (const float*)d_in[16];
  const float* gcb_b2   = (const float*)d_in[17];
  const float* gcb_bn2g = (const float*)d_in[18];
  const float* gcb_bn2b = (const float*)d_in[19];
  const float* gc7_w    = (const float*)d_in[20];
  const float* gc7_att  = (const float*)d_in[21];
  const float* gc7_b    = (const float*)d_in[22];
  float* out = (float*)d_out;

  float* ws   = (float*)d_ws;
  float* dct  = ws;
  float* x    = ws + 512;
  float* y    = ws + 169472;
  short* y_bf = (short*)(ws + 2332160);
  float* U    = ws + 3642880;
  // early
  short* w1T  = (short*)(U);
  short* w2T  = (short*)(U + 131072);
  short* kc1q = (short*)(U + 458752);
  float* key  = U + 1114112;
  float* q    = U + 2129920;
  float* att  = U + 2162688;
  short* x_bf = (short*)(U + 1114112);  // overlays key (dead after k_att)
  // late
  short* wgT  = (short*)(U);
  short* gc1wT= (short*)(U + 786432);
  float* h    = U + 790528;             // overlays x_bf (dead after gc1 layer)
  short* h_bf = (short*)(U + 2953216);
  // tail
  float* t2   = U;                      // overlays wgT (dead after loop)
  float* xo   = U + 168960;

  k_init_dct<<<1, 512, 0, stream>>>(dct);
  k_wconv1<<<1024, 256, 0, stream>>>(convK_w1, convQ_w1, w1T);
  k_wconv2<<<2560, 256, 0, stream>>>(convK_w2, convQ_w2, w2T);

  k_conv1<<<dim3(128,4), 256, 0, stream>>>(src, w1T, kc1q);
  k_conv2<<<dim3(128,4), 256, 0, stream>>>(kc1q, w2T, key, q);
  k_att<<<128, 64, 0, stream>>>(q, key, att);
  k_build_x<<<128, 256, 0, stream>>>(src, att, dct, x, x_bf);

  k_wgcn<<<6144, 256, 0, stream>>>(gcb_w1, gcb_w2, wgT);
  k_wgc1<<<32, 256, 0, stream>>>(gc1_w, gc1wT);

  k_layer<1><<<dim3(128,4), 256, 0, stream>>>(x_bf, gc1wT, gc1_att, gc1_b,
      bn1_g, bn1_b, nullptr, y, y_bf);

  for (int i = 0; i < 12; i++){
    k_layer<8><<<dim3(128,4), 256, 0, stream>>>(y_bf, wgT + i*65536,
        gcb_att1 + i*4356, gcb_b1 + i*256, gcb_bn1g + i*16896, gcb_bn1b + i*16896,
        nullptr, h, h_bf);
    k_layer<8><<<dim3(128,4), 256, 0, stream>>>(h_bf, wgT + (12+i)*65536,
        gcb_att2 + i*4356, gcb_b2 + i*256, gcb_bn2g + i*16896, gcb_bn2b + i*16896,
        y, y, y_bf);
  }

  k_gemm_n20<<<528, 320, 0, stream>>>(y, gc7_w, t2);
  k_amult20<<<128, 512, 0, stream>>>(t2, gc7_att, gc7_b, x, xo);
  k_out<<<128, 512, 0, stream>>>(xo, dct, out);
}

// Round 3
// 504.195 us; speedup vs baseline: 2.7865x; 1.4727x over previous
//
#include <hip/hip_runtime.h>
#include <hip/hip_bf16.h>

// HisRepItself round 3: mega-kernel for the whole GCN stack.
//  - convs/att/build_x/weight-prep: unchanged from round 2 (proven).
//  - k_mega: per-batch block (128 blocks x 256 thr) keeps y in LDS+f32 regs,
//    runs gc1 + 12 residual blocks (24 layers) + gc7 tail + idct + out.
//    GEMM1: t = y @ W (A from swizzled LDS, B from L2 global).
//    GEMM2 computed transposed: out'[f][n] = t_T[f][m] @ A[n][m].
//
// Workspace (f32 units), 3,290,624 floats = 13.2 MB:
//   dct 0 | x 512 | x_bf 169472 | wgT 333312 | gc1wT 1119744 | w1T 1123840
//   w2T 1254912 | kc1q 1582592 | key 2237952 | q 3253760 | att 3286528

typedef __attribute__((ext_vector_type(8))) short short8;
typedef __attribute__((ext_vector_type(4))) float float4v;

#define BNI 0.9999950000374995f

__device__ __forceinline__ short f2bf(float x){
  unsigned u = __float_as_uint(x);
  unsigned r = (u + 0x7fff + ((u >> 16) & 1)) >> 16;
  return (short)r;
}
__device__ __forceinline__ unsigned pk2(float a, float b){
  return (unsigned)(unsigned short)f2bf(a) | ((unsigned)(unsigned short)f2bf(b) << 16);
}
__device__ __forceinline__ float tanh_f(float x){
  x = fminf(fmaxf(x, -9.f), 9.f);
  float e = __expf(2.f * x);
  return (e - 1.f) * __builtin_amdgcn_rcpf(e + 1.f);
}

__global__ __launch_bounds__(512) void k_init_dct(float* dct){
  int t = threadIdx.x;
  if (t < 400){
    int k = t / 20, i = t % 20;
    double w = (k == 0) ? sqrt(1.0/20.0) : sqrt(2.0/20.0);
    dct[t] = (float)(w * cos(3.14159265358979323846 * (i + 0.5) * k / 20.0));
  }
}

// ---------------- weight prep (round-2 proven) ----------------
__global__ __launch_bounds__(256) void k_wconv1(const float* __restrict__ wK,
    const float* __restrict__ wQ, short* __restrict__ w1T){
  int idx = blockIdx.x*256 + threadIdx.x;
  if (idx >= 512*512) return;
  int f = idx >> 9, k = idx & 511;
  float v = 0.f;
  if (k < 396){
    int h = k / 66, c = k - h*66;
    const float* s = (f < 256) ? wK : wQ;
    v = s[((f & 255)*66 + c)*6 + h];
  }
  w1T[idx] = f2bf(v);
}

__global__ __launch_bounds__(256) void k_wconv2(const float* __restrict__ wK,
    const float* __restrict__ wQ, short* __restrict__ w2T){
  int idx = blockIdx.x*256 + threadIdx.x;
  if (idx >= 512*1280) return;
  int f = idx / 1280, k = idx - f*1280;
  int h = k >> 8, c = k & 255;
  const float* s = (f < 256) ? wK : wQ;
  w2T[idx] = f2bf(s[((f & 255)*256 + c)*5 + h]);
}

__global__ __launch_bounds__(256) void k_wgcn(const float* __restrict__ w1,
    const float* __restrict__ w2, short* __restrict__ wgT){
  int idx = blockIdx.x*256 + threadIdx.x;
  if (idx >= 24*65536) return;
  int l = idx >> 16, r = idx & 65535;
  int f = r >> 8, k = r & 255;
  const float* s = (l < 12) ? (w1 + l*65536) : (w2 + (l-12)*65536);
  wgT[idx] = f2bf(s[k*256 + f]);
}

__global__ __launch_bounds__(256) void k_wgc1(const float* __restrict__ w,
    short* __restrict__ wT){
  int idx = blockIdx.x*256 + threadIdx.x;
  if (idx >= 8192) return;
  int f = idx >> 5, k = idx & 31;
  wT[idx] = f2bf(k < 20 ? w[k*256 + f] : 0.f);
}

// ---------------- conv1 (round-2 proven) ----------------
__global__ __launch_bounds__(256) void k_conv1(const float* __restrict__ src,
    const short* __restrict__ w1T, short* __restrict__ kc1q){
  int b = blockIdx.x, ns = blockIdx.y;
  int f0 = ns*128;
  __shared__ short Aim[48*424];
  __shared__ short Wt[128*72];
  int tid = threadIdx.x;
  for (int idx = tid; idx < 48*424; idx += 256){
    int t = idx / 424, kk = idx - t*424;
    float v = 0.f;
    if (kk < 396 && t < 40){
      int h = kk / 66, c = kk - h*66;
      int row = t + h + ((t >= 35) ? 5 : 0);
      v = src[(b*50 + row)*66 + c] * 1e-3f;
    }
    Aim[idx] = f2bf(v);
  }
  int w = tid >> 6, lane = tid & 63, fl = lane & 15, g = lane >> 4;
  float4v acc[3][2];
  #pragma unroll
  for (int i=0;i<3;i++) for (int n=0;n<2;n++) acc[i][n] = (float4v){0.f,0.f,0.f,0.f};
  for (int kt = 0; kt < 416; kt += 64){
    __syncthreads();
    for (int ch = tid; ch < 128*8; ch += 256){
      int r = ch >> 3, kq = ch & 7;
      *(short8*)&Wt[r*72 + kq*8] = *(const short8*)&w1T[(f0 + r)*512 + kt + kq*8];
    }
    __syncthreads();
    int nst = (416 - kt >= 64) ? 2 : 1;
    for (int s = 0; s < nst; s++){
      int k0 = s*32;
      short8 bfr0 = *(const short8*)&Wt[(w*32 + fl)*72 + k0 + g*8];
      short8 bfr1 = *(const short8*)&Wt[(w*32 + 16 + fl)*72 + k0 + g*8];
      #pragma unroll
      for (int i=0;i<3;i++){
        short8 afr = *(const short8*)&Aim[(i*16 + fl)*424 + kt + k0 + g*8];
        acc[i][0] = __builtin_amdgcn_mfma_f32_16x16x32_bf16(afr, bfr0, acc[i][0], 0,0,0);
        acc[i][1] = __builtin_amdgcn_mfma_f32_16x16x32_bf16(afr, bfr1, acc[i][1], 0,0,0);
      }
    }
  }
  #pragma unroll
  for (int i=0;i<3;i++) for (int n=0;n<2;n++) for (int j=0;j<4;j++){
    int t = i*16 + g*4 + j;
    int f = f0 + w*32 + n*16 + fl;
    float v = fmaxf(acc[i][n][j], 0.f);
    if (t < 35 && f < 256) kc1q[(b*40 + t)*256 + f] = f2bf(v);
    else if (t >= 35 && t < 40 && f >= 256) kc1q[(b*40 + t)*256 + (f - 256)] = f2bf(v);
  }
}

// ---------------- conv2 (round-2 proven) ----------------
__global__ __launch_bounds__(256) void k_conv2(const short* __restrict__ kc1q,
    const short* __restrict__ w2T, float* __restrict__ key, float* __restrict__ q){
  int b = blockIdx.x, ns = blockIdx.y;
  int f0 = ns*128;
  __shared__ short kcs[40*256];
  __shared__ short Wt[128*136];
  char* kcb = (char*)kcs;
  int tid = threadIdx.x;
  for (int ch = tid; ch < 1280; ch += 256){
    int r = ch >> 5, kq = ch & 31;
    unsigned byte = (unsigned)(r*512 + kq*16) ^ (unsigned)((r & 7) << 4);
    *(short8*)(kcb + byte) = *(const short8*)&kc1q[(b*40 + r)*256 + kq*8];
  }
  int w = tid >> 6, lane = tid & 63, fl = lane & 15, g = lane >> 4;
  float4v acc[2][2];
  #pragma unroll
  for (int i=0;i<2;i++) for (int n=0;n<2;n++) acc[i][n] = (float4v){0.f,0.f,0.f,0.f};
  for (int kt = 0; kt < 1280; kt += 128){
    __syncthreads();
    for (int ch = tid; ch < 128*16; ch += 256){
      int r = ch >> 4, kq = ch & 15;
      *(short8*)&Wt[r*136 + kq*8] = *(const short8*)&w2T[(f0 + r)*1280 + kt + kq*8];
    }
    __syncthreads();
    #pragma unroll
    for (int s = 0; s < 4; s++){
      int k = kt + s*32;
      int h = k >> 8, cb = k & 255;
      short8 bfr0 = *(const short8*)&Wt[(w*32 + fl)*136 + s*32 + g*8];
      short8 bfr1 = *(const short8*)&Wt[(w*32 + 16 + fl)*136 + s*32 + g*8];
      #pragma unroll
      for (int i=0;i<2;i++){
        int t = i*16 + fl;
        int row = t + h + ((t == 31) ? 4 : 0);
        unsigned byte = (unsigned)(row*512 + (cb + g*8)*2) ^ (unsigned)((row & 7) << 4);
        short8 afr = *(const short8*)(kcb + byte);
        acc[i][0] = __builtin_amdgcn_mfma_f32_16x16x32_bf16(afr, bfr0, acc[i][0], 0,0,0);
        acc[i][1] = __builtin_amdgcn_mfma_f32_16x16x32_bf16(afr, bfr1, acc[i][1], 0,0,0);
      }
    }
  }
  #pragma unroll
  for (int i=0;i<2;i++) for (int n=0;n<2;n++) for (int j=0;j<4;j++){
    int t = i*16 + g*4 + j;
    int f = f0 + w*32 + n*16 + fl;
    float v = fmaxf(acc[i][n][j], 0.f);
    if (t < 31 && f < 256) key[(b*31 + t)*256 + f] = v;
    else if (t == 31 && f >= 256) q[b*256 + f - 256] = v;
  }
}

// ---------------- attention + build_x (round-2 proven) ----------------
__global__ __launch_bounds__(64) void k_att(const float* __restrict__ q,
    const float* __restrict__ key, float* __restrict__ att){
  int b = blockIdx.x;
  int lane = threadIdx.x;
  float s = 0.f;
  if (lane < 31){
    const float* kr = key + (b*31 + lane)*256;
    const float* qr = q + b*256;
    for (int o = 0; o < 256; o++) s += qr[o] * kr[o];
    s += 1e-15f;
  }
  float tot = s;
  for (int off = 32; off; off >>= 1) tot += __shfl_down(tot, off);
  tot = __shfl(tot, 0);
  if (lane < 31) att[b*32 + lane] = s / tot;
}

__global__ __launch_bounds__(256) void k_build_x(const float* __restrict__ src,
    const float* __restrict__ att, const float* __restrict__ dct,
    float* __restrict__ x, short* __restrict__ x_bf){
  int b = blockIdx.x;
  int tid = threadIdx.x;
  __shared__ float z[20*66];
  __shared__ float a[31];
  for (int i = tid; i < 2560; i += 256) x_bf[b*2560 + i] = 0;
  if (tid < 31) a[tid] = att[b*32 + tid];
  __syncthreads();
  for (int idx = tid; idx < 1320; idx += 256){
    int i = idx / 66, f = idx % 66;
    float s = 0.f;
    for (int v = 0; v < 31; v++) s += a[v] * src[(b*50 + v + i)*66 + f];
    z[idx] = s;
  }
  __syncthreads();
  for (int idx = tid; idx < 660; idx += 256){
    int f = idx / 10, k = idx % 10;
    float s1 = 0.f, s2 = 0.f;
    #pragma unroll
    for (int i = 0; i < 20; i++){
      float d = dct[k*20 + i];
      int tt = (i < 10) ? (40 + i) : 49;
      s1 += d * src[(b*50 + tt)*66 + f];
      s2 += d * z[i*66 + f];
    }
    x[(b*66 + f)*20 + k] = s1;
    x[(b*66 + f)*20 + 10 + k] = s2;
    x_bf[(b*80 + f)*32 + k] = f2bf(s1);
    x_bf[(b*80 + f)*32 + 10 + k] = f2bf(s2);
  }
}

// ---------------- mega kernel ----------------
// LDS tiles (all XOR-swizzled byte ^= ((row&7)<<4)):
//   ybf: [80 m][512 B]   current layer input, bf16
//   tT : [256 f][256 B]  t transposed (m-extent 96, zero-padded), bf16
//   am : [80 n][256 B]   A matrix row-major (m pad 96), bf16 / also w7 [32][512B]

__device__ __forceinline__ void stage_Am(const float* __restrict__ Af, int tid,
    char* am_c){
  for (int i = tid; i < 1920; i += 256){
    int n = i / 24, mq = (i % 24) * 4;
    float v0=0.f, v1=0.f, v2=0.f, v3=0.f;
    if (n < 66){
      if (mq+0 < 66) v0 = Af[n*66 + mq+0];
      if (mq+1 < 66) v1 = Af[n*66 + mq+1];
      if (mq+2 < 66) v2 = Af[n*66 + mq+2];
      if (mq+3 < 66) v3 = Af[n*66 + mq+3];
    }
    uint2 u; u.x = pk2(v0, v1); u.y = pk2(v2, v3);
    *(uint2*)(am_c + n*256 + ((mq*2) ^ ((n & 7) << 4))) = u;
  }
}

template<int KSTEPS>
__device__ __forceinline__ void do_g1(const short* __restrict__ Wg, int kstride,
    int w, int fl, int g, const char* ybf_c, char* tT_c){
  float4v acc[5][4];
  #pragma unroll
  for (int i=0;i<5;i++)
    #pragma unroll
    for (int n=0;n<4;n++) acc[i][n] = (float4v){0.f,0.f,0.f,0.f};
  #pragma unroll
  for (int ks = 0; ks < KSTEPS; ks++){
    short8 bf[4];
    #pragma unroll
    for (int n=0;n<4;n++)
      bf[n] = *(const short8*)&Wg[(w*64 + n*16 + fl)*kstride + ks*32 + g*8];
    #pragma unroll
    for (int i=0;i<5;i++){
      int m = i*16 + fl;
      short8 af = *(const short8*)(ybf_c + m*512 + (((ks*32 + g*8)*2) ^ ((m & 7) << 4)));
      #pragma unroll
      for (int n=0;n<4;n++)
        acc[i][n] = __builtin_amdgcn_mfma_f32_16x16x32_bf16(af, bf[n], acc[i][n], 0,0,0);
    }
  }
  #pragma unroll
  for (int i=0;i<5;i++){
    int mb = (i*16 + g*4)*2;
    #pragma unroll
    for (int n=0;n<4;n++){
      int f = w*64 + n*16 + fl;
      uint2 u; u.x = pk2(acc[i][n][0], acc[i][n][1]); u.y = pk2(acc[i][n][2], acc[i][n][3]);
      *(uint2*)(tT_c + f*256 + (mb ^ ((f & 7) << 4))) = u;
    }
  }
}

// MODE: 0 = y_r = v (entry), 1 = h (no residual), 2 = y_r += v
template<int MODE>
__device__ __forceinline__ void do_g2(const float* __restrict__ bias,
    const float* __restrict__ gg, const float* __restrict__ be,
    float4v y_r[4][5], int w, int fl, int g,
    const char* tT_c, const char* am_c, char* ybf_c){
  float4v acc[4][5];
  #pragma unroll
  for (int i=0;i<4;i++)
    #pragma unroll
    for (int n=0;n<5;n++) acc[i][n] = (float4v){0.f,0.f,0.f,0.f};
  #pragma unroll
  for (int ks = 0; ks < 3; ks++){
    short8 bA[5];
    #pragma unroll
    for (int n2=0;n2<5;n2++){
      int n = n2*16 + fl;
      bA[n2] = *(const short8*)(am_c + n*256 + (((ks*32 + g*8)*2) ^ ((n & 7) << 4)));
    }
    #pragma unroll
    for (int i2=0;i2<4;i2++){
      int f = w*64 + i2*16 + fl;
      short8 af = *(const short8*)(tT_c + f*256 + (((ks*32 + g*8)*2) ^ ((f & 7) << 4)));
      #pragma unroll
      for (int n2=0;n2<5;n2++)
        acc[i2][n2] = __builtin_amdgcn_mfma_f32_16x16x32_bf16(af, bA[n2], acc[i2][n2], 0,0,0);
    }
  }
  #pragma unroll
  for (int i2=0;i2<4;i2++){
    #pragma unroll
    for (int n2=0;n2<5;n2++){
      int n = n2*16 + fl;
      bool nok = (n < 66);
      int nsafe = nok ? n : 0;
      float vv[4];
      #pragma unroll
      for (int j=0;j<4;j++){
        int f = w*64 + i2*16 + g*4 + j;
        float v = acc[i2][n2][j] + bias[f];
        int bi = nsafe*256 + f;
        v = v * (gg[bi] * BNI) + be[bi];
        v = tanh_f(v);
        if (MODE == 0) y_r[i2][n2] [j] = v;
        if (MODE == 2){ v += y_r[i2][n2][j]; y_r[i2][n2][j] = v; }
        vv[j] = nok ? v : 0.f;
      }
      int fb2 = (w*64 + i2*16 + g*4)*2;
      int byte = n*512 + (fb2 ^ ((n & 7) << 4));
      *(unsigned*)(ybf_c + byte) = pk2(vv[0], vv[1]);
      *(unsigned*)(ybf_c + byte + 4) = pk2(vv[2], vv[3]);
    }
  }
}

__global__ __launch_bounds__(256) void k_mega(const short* __restrict__ x_bf,
    const short* __restrict__ gc1wT, const short* __restrict__ wgT,
    const float* __restrict__ gc1_att, const float* __restrict__ gc1_b,
    const float* __restrict__ bn1_g, const float* __restrict__ bn1_b,
    const float* __restrict__ a1, const float* __restrict__ b1,
    const float* __restrict__ g1, const float* __restrict__ be1,
    const float* __restrict__ a2, const float* __restrict__ b2,
    const float* __restrict__ g2, const float* __restrict__ be2,
    const float* __restrict__ gc7_w, const float* __restrict__ gc7_att,
    const float* __restrict__ gc7_b, const float* __restrict__ x,
    const float* __restrict__ dct, float* __restrict__ out)
{
  __shared__ __align__(16) char ybf_c[40960];
  __shared__ __align__(16) char tT_c[65536];
  __shared__ __align__(16) char am_c[20480];
  __shared__ float xo_l[1320];
  __shared__ float dct_l[400];

  int b = blockIdx.x, tid = threadIdx.x;
  int w = tid >> 6, lane = tid & 63, fl = lane & 15, g = lane >> 4;

  for (int i = tid; i < 4096; i += 256) ((float4v*)tT_c)[i] = (float4v){0.f,0.f,0.f,0.f};
  for (int i = tid; i < 400; i += 256) dct_l[i] = dct[i];
  for (int i = tid; i < 320; i += 256){
    int m = i >> 2, kq = i & 3;
    short8 v = *(const short8*)&x_bf[(b*80 + m)*32 + kq*8];
    *(short8*)(ybf_c + m*512 + ((kq*16) ^ ((m & 7) << 4))) = v;
  }
  __syncthreads();

  float4v y_r[4][5];

  // entry layer (gc1, K=32)
  stage_Am(gc1_att, tid, am_c);
  do_g1<1>(gc1wT, 32, w, fl, g, ybf_c, tT_c);
  __syncthreads();
  do_g2<0>(gc1_b, bn1_g, bn1_b, y_r, w, fl, g, tT_c, am_c, ybf_c);
  __syncthreads();

  for (int l = 0; l < 12; l++){
    stage_Am(a1 + l*4356, tid, am_c);
    do_g1<8>(wgT + l*65536, 256, w, fl, g, ybf_c, tT_c);
    __syncthreads();
    do_g2<1>(b1 + l*256, g1 + (long)l*16896, be1 + (long)l*16896, y_r, w, fl, g,
             tT_c, am_c, ybf_c);
    __syncthreads();
    stage_Am(a2 + l*4356, tid, am_c);
    do_g1<8>(wgT + (12 + l)*65536, 256, w, fl, g, ybf_c, tT_c);
    __syncthreads();
    do_g2<2>(b2 + l*256, g2 + (long)l*16896, be2 + (long)l*16896, y_r, w, fl, g,
             tT_c, am_c, ybf_c);
    __syncthreads();
  }

  // ---- gc7 tail ----
  // stage w7 [32 f][256 k] bf16 into am region (rows 512 B, same swizzle)
  for (int i = tid; i < 2048; i += 256){
    int f = i >> 6, kq = (i & 63)*4;
    float v0=0.f, v1=0.f, v2=0.f, v3=0.f;
    if (f < 20){
      v0 = gc7_w[(kq+0)*20 + f]; v1 = gc7_w[(kq+1)*20 + f];
      v2 = gc7_w[(kq+2)*20 + f]; v3 = gc7_w[(kq+3)*20 + f];
    }
    uint2 u; u.x = pk2(v0, v1); u.y = pk2(v2, v3);
    *(uint2*)(am_c + f*512 + ((kq*2) ^ ((f & 7) << 4))) = u;
  }
  __syncthreads();

  // G1t: t2 = y @ w7 (N=32, K=256), all waves redundant
  float4v at[5][2];
  #pragma unroll
  for (int i=0;i<5;i++){ at[i][0] = (float4v){0.f,0.f,0.f,0.f}; at[i][1] = (float4v){0.f,0.f,0.f,0.f}; }
  #pragma unroll
  for (int ks = 0; ks < 8; ks++){
    short8 bf[2];
    #pragma unroll
    for (int n=0;n<2;n++){
      int f = n*16 + fl;
      bf[n] = *(const short8*)(am_c + f*512 + (((ks*32 + g*8)*2) ^ ((f & 7) << 4)));
    }
    #pragma unroll
    for (int i=0;i<5;i++){
      int m = i*16 + fl;
      short8 af = *(const short8*)(ybf_c + m*512 + (((ks*32 + g*8)*2) ^ ((m & 7) << 4)));
      at[i][0] = __builtin_amdgcn_mfma_f32_16x16x32_bf16(af, bf[0], at[i][0], 0,0,0);
      at[i][1] = __builtin_amdgcn_mfma_f32_16x16x32_bf16(af, bf[1], at[i][1], 0,0,0);
    }
  }
  if (w == 0){
    #pragma unroll
    for (int i=0;i<5;i++){
      int mb = (i*16 + g*4)*2;
      #pragma unroll
      for (int n=0;n<2;n++){
        int f = n*16 + fl;
        uint2 u; u.x = pk2(at[i][n][0], at[i][n][1]); u.y = pk2(at[i][n][2], at[i][n][3]);
        *(uint2*)(tT_c + f*256 + (mb ^ ((f & 7) << 4))) = u;
      }
    }
  }
  __syncthreads();
  stage_Am(gc7_att, tid, am_c);
  __syncthreads();

  // G2't: out'[f32][n80] = t2_T @ A7^T, all waves redundant, wave0 epilogue
  float4v a2t[2][5];
  #pragma unroll
  for (int i=0;i<2;i++)
    #pragma unroll
    for (int n=0;n<5;n++) a2t[i][n] = (float4v){0.f,0.f,0.f,0.f};
  #pragma unroll
  for (int ks = 0; ks < 3; ks++){
    short8 bA[5];
    #pragma unroll
    for (int n2=0;n2<5;n2++){
      int n = n2*16 + fl;
      bA[n2] = *(const short8*)(am_c + n*256 + (((ks*32 + g*8)*2) ^ ((n & 7) << 4)));
    }
    #pragma unroll
    for (int i2=0;i2<2;i2++){
      int f = i2*16 + fl;
      short8 af = *(const short8*)(tT_c + f*256 + (((ks*32 + g*8)*2) ^ ((f & 7) << 4)));
      #pragma unroll
      for (int n2=0;n2<5;n2++)
        a2t[i2][n2] = __builtin_amdgcn_mfma_f32_16x16x32_bf16(af, bA[n2], a2t[i2][n2], 0,0,0);
    }
  }
  if (w == 0){
    #pragma unroll
    for (int i2=0;i2<2;i2++){
      #pragma unroll
      for (int n2=0;n2<5;n2++){
        int n = n2*16 + fl;
        #pragma unroll
        for (int j=0;j<4;j++){
          int f = i2*16 + g*4 + j;
          if (f < 20 && n < 66)
            xo_l[n*20 + f] = a2t[i2][n2][j] + gc7_b[f] + x[(b*66 + n)*20 + f];
        }
      }
    }
  }
  __syncthreads();

  for (int idx = tid; idx < 1320; idx += 256){
    int r = idx / 66, fn = idx % 66;
    float s = 0.f;
    #pragma unroll
    for (int k = 0; k < 10; k++) s += dct_l[k*20 + r] * xo_l[fn*20 + k];
    out[(b*20 + r)*66 + fn] = s;
  }
}

extern "C" void kernel_launch(void* const* d_in, const int* in_sizes, int n_in,
                              void* d_out, int out_size, void* d_ws, size_t ws_size,
                              hipStream_t stream) {
  const float* src      = (const float*)d_in[0];
  const float* convQ_w1 = (const float*)d_in[1];
  const float* convQ_w2 = (const float*)d_in[2];
  const float* convK_w1 = (const float*)d_in[3];
  const float* convK_w2 = (const float*)d_in[4];
  const float* gc1_w    = (const float*)d_in[5];
  const float* gc1_att  = (const float*)d_in[6];
  const float* gc1_b    = (const float*)d_in[7];
  const float* bn1_g    = (const float*)d_in[8];
  const float* bn1_b    = (const float*)d_in[9];
  const float* gcb_w1   = (const float*)d_in[10];
  const float* gcb_att1 = (const float*)d_in[11];
  const float* gcb_b1   = (const float*)d_in[12];
  const float* gcb_bn1g = (const float*)d_in[13];
  const float* gcb_bn1b = (const float*)d_in[14];
  const float* gcb_w2   = (const float*)d_in[15];
  const float* gcb_att2 = (const float*)d_in[16];
  const float* gcb_b2   = (const float*)d_in[17];
  const float* gcb_bn2g = (const float*)d_in[18];
  const float* gcb_bn2b = (const float*)d_in[19];
  const float* gc7_w    = (const float*)d_in[20];
  const float* gc7_att  = (const float*)d_in[21];
  const float* gc7_b    = (const float*)d_in[22];
  float* out = (float*)d_out;

  float* ws    = (float*)d_ws;
  float* dct   = ws;
  float* x     = ws + 512;
  short* x_bf  = (short*)(ws + 169472);
  short* wgT   = (short*)(ws + 333312);
  short* gc1wT = (short*)(ws + 1119744);
  short* w1T   = (short*)(ws + 1123840);
  short* w2T   = (short*)(ws + 1254912);
  short* kc1q  = (short*)(ws + 1582592);
  float* key   = ws + 2237952;
  float* q     = ws + 3253760;
  float* att   = ws + 3286528;

  k_init_dct<<<1, 512, 0, stream>>>(dct);
  k_wconv1<<<1024, 256, 0, stream>>>(convK_w1, convQ_w1, w1T);
  k_wconv2<<<2560, 256, 0, stream>>>(convK_w2, convQ_w2, w2T);
  k_wgcn<<<6144, 256, 0, stream>>>(gcb_w1, gcb_w2, wgT);
  k_wgc1<<<32, 256, 0, stream>>>(gc1_w, gc1wT);

  k_conv1<<<dim3(128,4), 256, 0, stream>>>(src, w1T, kc1q);
  k_conv2<<<dim3(128,4), 256, 0, stream>>>(kc1q, w2T, key, q);
  k_att<<<128, 64, 0, stream>>>(q, key, att);
  k_build_x<<<128, 256, 0, stream>>>(src, att, dct, x, x_bf);

  k_mega<<<128, 256, 0, stream>>>(x_bf, gc1wT, wgT,
      gc1_att, gc1_b, bn1_g, bn1_b,
      gcb_att1, gcb_b1, gcb_bn1g, gcb_bn1b,
      gcb_att2, gcb_b2, gcb_bn2g, gcb_bn2b,
      gc7_w, gc7_att, gc7_b, x, dct, out);
}

// Round 4
// 359.430 us; speedup vs baseline: 3.9087x; 1.4028x over previous
//
#include <hip/hip_runtime.h>
#include <hip/hip_bf16.h>

// HisRepItself round 4: mega-kernel gets 8 waves + latency overlap.
//  - k_mega: 512 thr (8 waves), per-wave 32-wide f-split of both GEMMs,
//    T14 split A-staging (load before GEMM1, write after), (row&15)<<4 swizzle.
//  - convs/att/build_x/weight-prep unchanged (proven).
//
// Workspace (f32 units), 3,290,624 floats = 13.2 MB:
//   dct 0 | x 512 | x_bf 169472 | wgT 333312 | gc1wT 1119744 | w1T 1123840
//   w2T 1254912 | kc1q 1582592 | key 2237952 | q 3253760 | att 3286528

typedef __attribute__((ext_vector_type(8))) short short8;
typedef __attribute__((ext_vector_type(4))) float float4v;

#define BNI 0.9999950000374995f

__device__ __forceinline__ short f2bf(float x){
  unsigned u = __float_as_uint(x);
  unsigned r = (u + 0x7fff + ((u >> 16) & 1)) >> 16;
  return (short)r;
}
__device__ __forceinline__ unsigned pk2(float a, float b){
  return (unsigned)(unsigned short)f2bf(a) | ((unsigned)(unsigned short)f2bf(b) << 16);
}
__device__ __forceinline__ float tanh_f(float x){
  x = fminf(fmaxf(x, -9.f), 9.f);
  float e = __expf(2.f * x);
  return (e - 1.f) * __builtin_amdgcn_rcpf(e + 1.f);
}

__global__ __launch_bounds__(512) void k_init_dct(float* dct){
  int t = threadIdx.x;
  if (t < 400){
    int k = t / 20, i = t % 20;
    double w = (k == 0) ? sqrt(1.0/20.0) : sqrt(2.0/20.0);
    dct[t] = (float)(w * cos(3.14159265358979323846 * (i + 0.5) * k / 20.0));
  }
}

// ---------------- weight prep (proven) ----------------
__global__ __launch_bounds__(256) void k_wconv1(const float* __restrict__ wK,
    const float* __restrict__ wQ, short* __restrict__ w1T){
  int idx = blockIdx.x*256 + threadIdx.x;
  if (idx >= 512*512) return;
  int f = idx >> 9, k = idx & 511;
  float v = 0.f;
  if (k < 396){
    int h = k / 66, c = k - h*66;
    const float* s = (f < 256) ? wK : wQ;
    v = s[((f & 255)*66 + c)*6 + h];
  }
  w1T[idx] = f2bf(v);
}

__global__ __launch_bounds__(256) void k_wconv2(const float* __restrict__ wK,
    const float* __restrict__ wQ, short* __restrict__ w2T){
  int idx = blockIdx.x*256 + threadIdx.x;
  if (idx >= 512*1280) return;
  int f = idx / 1280, k = idx - f*1280;
  int h = k >> 8, c = k & 255;
  const float* s = (f < 256) ? wK : wQ;
  w2T[idx] = f2bf(s[((f & 255)*256 + c)*5 + h]);
}

__global__ __launch_bounds__(256) void k_wgcn(const float* __restrict__ w1,
    const float* __restrict__ w2, short* __restrict__ wgT){
  int idx = blockIdx.x*256 + threadIdx.x;
  if (idx >= 24*65536) return;
  int l = idx >> 16, r = idx & 65535;
  int f = r >> 8, k = r & 255;
  const float* s = (l < 12) ? (w1 + l*65536) : (w2 + (l-12)*65536);
  wgT[idx] = f2bf(s[k*256 + f]);
}

__global__ __launch_bounds__(256) void k_wgc1(const float* __restrict__ w,
    short* __restrict__ wT){
  int idx = blockIdx.x*256 + threadIdx.x;
  if (idx >= 8192) return;
  int f = idx >> 5, k = idx & 31;
  wT[idx] = f2bf(k < 20 ? w[k*256 + f] : 0.f);
}

// ---------------- conv1 (proven) ----------------
__global__ __launch_bounds__(256) void k_conv1(const float* __restrict__ src,
    const short* __restrict__ w1T, short* __restrict__ kc1q){
  int b = blockIdx.x, ns = blockIdx.y;
  int f0 = ns*128;
  __shared__ short Aim[48*424];
  __shared__ short Wt[128*72];
  int tid = threadIdx.x;
  for (int idx = tid; idx < 48*424; idx += 256){
    int t = idx / 424, kk = idx - t*424;
    float v = 0.f;
    if (kk < 396 && t < 40){
      int h = kk / 66, c = kk - h*66;
      int row = t + h + ((t >= 35) ? 5 : 0);
      v = src[(b*50 + row)*66 + c] * 1e-3f;
    }
    Aim[idx] = f2bf(v);
  }
  int w = tid >> 6, lane = tid & 63, fl = lane & 15, g = lane >> 4;
  float4v acc[3][2];
  #pragma unroll
  for (int i=0;i<3;i++) for (int n=0;n<2;n++) acc[i][n] = (float4v){0.f,0.f,0.f,0.f};
  for (int kt = 0; kt < 416; kt += 64){
    __syncthreads();
    for (int ch = tid; ch < 128*8; ch += 256){
      int r = ch >> 3, kq = ch & 7;
      *(short8*)&Wt[r*72 + kq*8] = *(const short8*)&w1T[(f0 + r)*512 + kt + kq*8];
    }
    __syncthreads();
    int nst = (416 - kt >= 64) ? 2 : 1;
    for (int s = 0; s < nst; s++){
      int k0 = s*32;
      short8 bfr0 = *(const short8*)&Wt[(w*32 + fl)*72 + k0 + g*8];
      short8 bfr1 = *(const short8*)&Wt[(w*32 + 16 + fl)*72 + k0 + g*8];
      #pragma unroll
      for (int i=0;i<3;i++){
        short8 afr = *(const short8*)&Aim[(i*16 + fl)*424 + kt + k0 + g*8];
        acc[i][0] = __builtin_amdgcn_mfma_f32_16x16x32_bf16(afr, bfr0, acc[i][0], 0,0,0);
        acc[i][1] = __builtin_amdgcn_mfma_f32_16x16x32_bf16(afr, bfr1, acc[i][1], 0,0,0);
      }
    }
  }
  #pragma unroll
  for (int i=0;i<3;i++) for (int n=0;n<2;n++) for (int j=0;j<4;j++){
    int t = i*16 + g*4 + j;
    int f = f0 + w*32 + n*16 + fl;
    float v = fmaxf(acc[i][n][j], 0.f);
    if (t < 35 && f < 256) kc1q[(b*40 + t)*256 + f] = f2bf(v);
    else if (t >= 35 && t < 40 && f >= 256) kc1q[(b*40 + t)*256 + (f - 256)] = f2bf(v);
  }
}

// ---------------- conv2 (proven) ----------------
__global__ __launch_bounds__(256) void k_conv2(const short* __restrict__ kc1q,
    const short* __restrict__ w2T, float* __restrict__ key, float* __restrict__ q){
  int b = blockIdx.x, ns = blockIdx.y;
  int f0 = ns*128;
  __shared__ short kcs[40*256];
  __shared__ short Wt[128*136];
  char* kcb = (char*)kcs;
  int tid = threadIdx.x;
  for (int ch = tid; ch < 1280; ch += 256){
    int r = ch >> 5, kq = ch & 31;
    unsigned byte = (unsigned)(r*512 + kq*16) ^ (unsigned)((r & 7) << 4);
    *(short8*)(kcb + byte) = *(const short8*)&kc1q[(b*40 + r)*256 + kq*8];
  }
  int w = tid >> 6, lane = tid & 63, fl = lane & 15, g = lane >> 4;
  float4v acc[2][2];
  #pragma unroll
  for (int i=0;i<2;i++) for (int n=0;n<2;n++) acc[i][n] = (float4v){0.f,0.f,0.f,0.f};
  for (int kt = 0; kt < 1280; kt += 128){
    __syncthreads();
    for (int ch = tid; ch < 128*16; ch += 256){
      int r = ch >> 4, kq = ch & 15;
      *(short8*)&Wt[r*136 + kq*8] = *(const short8*)&w2T[(f0 + r)*1280 + kt + kq*8];
    }
    __syncthreads();
    #pragma unroll
    for (int s = 0; s < 4; s++){
      int k = kt + s*32;
      int h = k >> 8, cb = k & 255;
      short8 bfr0 = *(const short8*)&Wt[(w*32 + fl)*136 + s*32 + g*8];
      short8 bfr1 = *(const short8*)&Wt[(w*32 + 16 + fl)*136 + s*32 + g*8];
      #pragma unroll
      for (int i=0;i<2;i++){
        int t = i*16 + fl;
        int row = t + h + ((t == 31) ? 4 : 0);
        unsigned byte = (unsigned)(row*512 + (cb + g*8)*2) ^ (unsigned)((row & 7) << 4);
        short8 afr = *(const short8*)(kcb + byte);
        acc[i][0] = __builtin_amdgcn_mfma_f32_16x16x32_bf16(afr, bfr0, acc[i][0], 0,0,0);
        acc[i][1] = __builtin_amdgcn_mfma_f32_16x16x32_bf16(afr, bfr1, acc[i][1], 0,0,0);
      }
    }
  }
  #pragma unroll
  for (int i=0;i<2;i++) for (int n=0;n<2;n++) for (int j=0;j<4;j++){
    int t = i*16 + g*4 + j;
    int f = f0 + w*32 + n*16 + fl;
    float v = fmaxf(acc[i][n][j], 0.f);
    if (t < 31 && f < 256) key[(b*31 + t)*256 + f] = v;
    else if (t == 31 && f >= 256) q[b*256 + f - 256] = v;
  }
}

// ---------------- attention + build_x (proven) ----------------
__global__ __launch_bounds__(64) void k_att(const float* __restrict__ q,
    const float* __restrict__ key, float* __restrict__ att){
  int b = blockIdx.x;
  int lane = threadIdx.x;
  float s = 0.f;
  if (lane < 31){
    const float* kr = key + (b*31 + lane)*256;
    const float* qr = q + b*256;
    for (int o = 0; o < 256; o++) s += qr[o] * kr[o];
    s += 1e-15f;
  }
  float tot = s;
  for (int off = 32; off; off >>= 1) tot += __shfl_down(tot, off);
  tot = __shfl(tot, 0);
  if (lane < 31) att[b*32 + lane] = s / tot;
}

__global__ __launch_bounds__(256) void k_build_x(const float* __restrict__ src,
    const float* __restrict__ att, const float* __restrict__ dct,
    float* __restrict__ x, short* __restrict__ x_bf){
  int b = blockIdx.x;
  int tid = threadIdx.x;
  __shared__ float z[20*66];
  __shared__ float a[31];
  for (int i = tid; i < 2560; i += 256) x_bf[b*2560 + i] = 0;
  if (tid < 31) a[tid] = att[b*32 + tid];
  __syncthreads();
  for (int idx = tid; idx < 1320; idx += 256){
    int i = idx / 66, f = idx % 66;
    float s = 0.f;
    for (int v = 0; v < 31; v++) s += a[v] * src[(b*50 + v + i)*66 + f];
    z[idx] = s;
  }
  __syncthreads();
  for (int idx = tid; idx < 660; idx += 256){
    int f = idx / 10, k = idx % 10;
    float s1 = 0.f, s2 = 0.f;
    #pragma unroll
    for (int i = 0; i < 20; i++){
      float d = dct[k*20 + i];
      int tt = (i < 10) ? (40 + i) : 49;
      s1 += d * src[(b*50 + tt)*66 + f];
      s2 += d * z[i*66 + f];
    }
    x[(b*66 + f)*20 + k] = s1;
    x[(b*66 + f)*20 + 10 + k] = s2;
    x_bf[(b*80 + f)*32 + k] = f2bf(s1);
    x_bf[(b*80 + f)*32 + 10 + k] = f2bf(s2);
  }
}

// ---------------- mega kernel (8 waves) ----------------
// LDS tiles (all XOR-swizzled byte ^= ((row&15)<<4)):
//   ybf: [80 m][512 B]   layer input, bf16
//   tT : [256 f][256 B]  t transposed (m-extent 96, zero-padded), bf16
//   am : [80 n][256 B]   A row-major (m pad 96), bf16 / w7 as [32][512 B]

// T14 split A-staging: load phase (regs) ... write phase (LDS)
__device__ __forceinline__ void am_addr(int i, const float* __restrict__ Af,
    uint2* u, int* byt){
  int n = i / 24, mq = (i % 24) * 4;
  float v0=0.f, v1=0.f, v2=0.f, v3=0.f;
  if (n < 66){
    if (mq+0 < 66) v0 = Af[n*66 + mq+0];
    if (mq+1 < 66) v1 = Af[n*66 + mq+1];
    if (mq+2 < 66) v2 = Af[n*66 + mq+2];
    if (mq+3 < 66) v3 = Af[n*66 + mq+3];
  }
  u->x = pk2(v0, v1); u->y = pk2(v2, v3);
  *byt = n*256 + ((mq*2) ^ ((n & 15) << 4));
}

// plain staged A (tail use)
__device__ __forceinline__ void stage_Am(const float* __restrict__ Af, int tid,
    char* am_c){
  for (int i = tid; i < 1920; i += 512){
    uint2 u; int byt;
    am_addr(i, Af, &u, &byt);
    *(uint2*)(am_c + byt) = u;
  }
}

// GEMM1: tT[f][m] = (ybf[m][k] @ W[k][f])^T ; wave w covers f in [32w,32w+32)
template<int KSTEPS>
__device__ __forceinline__ void do_g1(const short* __restrict__ Wg, int kstride,
    int w, int fl, int g, const char* ybf_c, char* tT_c){
  float4v acc[5][2];
  #pragma unroll
  for (int i=0;i<5;i++)
    #pragma unroll
    for (int n=0;n<2;n++) acc[i][n] = (float4v){0.f,0.f,0.f,0.f};
  #pragma unroll
  for (int ks = 0; ks < KSTEPS; ks++){
    short8 bf[2];
    #pragma unroll
    for (int n=0;n<2;n++)
      bf[n] = *(const short8*)&Wg[(w*32 + n*16 + fl)*kstride + ks*32 + g*8];
    #pragma unroll
    for (int i=0;i<5;i++){
      int m = i*16 + fl;
      short8 af = *(const short8*)(ybf_c + m*512 + (((ks*32 + g*8)*2) ^ ((m & 15) << 4)));
      #pragma unroll
      for (int n=0;n<2;n++)
        acc[i][n] = __builtin_amdgcn_mfma_f32_16x16x32_bf16(af, bf[n], acc[i][n], 0,0,0);
    }
  }
  #pragma unroll
  for (int i=0;i<5;i++){
    int mb = (i*16 + g*4)*2;
    #pragma unroll
    for (int n=0;n<2;n++){
      int f = w*32 + n*16 + fl;
      uint2 u; u.x = pk2(acc[i][n][0], acc[i][n][1]); u.y = pk2(acc[i][n][2], acc[i][n][3]);
      *(uint2*)(tT_c + f*256 + (mb ^ ((f & 15) << 4))) = u;
    }
  }
}

// GEMM2 + epilogue; wave w covers f in [32w,32w+32); MODE: 0 set y_r, 1 none, 2 +=
template<int MODE>
__device__ __forceinline__ void do_g2(const float* __restrict__ bias,
    const float* __restrict__ gg, const float* __restrict__ be,
    float4v (&y_r)[2][5], int w, int fl, int g,
    const char* tT_c, const char* am_c, char* ybf_c){
  float4v acc[2][5];
  #pragma unroll
  for (int i=0;i<2;i++)
    #pragma unroll
    for (int n=0;n<5;n++) acc[i][n] = (float4v){0.f,0.f,0.f,0.f};
  #pragma unroll
  for (int ks = 0; ks < 3; ks++){
    short8 bA[5];
    #pragma unroll
    for (int n2=0;n2<5;n2++){
      int n = n2*16 + fl;
      bA[n2] = *(const short8*)(am_c + n*256 + (((ks*32 + g*8)*2) ^ ((n & 15) << 4)));
    }
    #pragma unroll
    for (int i2=0;i2<2;i2++){
      int f = w*32 + i2*16 + fl;
      short8 af = *(const short8*)(tT_c + f*256 + (((ks*32 + g*8)*2) ^ ((f & 15) << 4)));
      #pragma unroll
      for (int n2=0;n2<5;n2++)
        acc[i2][n2] = __builtin_amdgcn_mfma_f32_16x16x32_bf16(af, bA[n2], acc[i2][n2], 0,0,0);
    }
  }
  #pragma unroll
  for (int i2=0;i2<2;i2++){
    #pragma unroll
    for (int n2=0;n2<5;n2++){
      int n = n2*16 + fl;
      bool nok = (n < 66);
      int nsafe = nok ? n : 0;
      float vv[4];
      #pragma unroll
      for (int j=0;j<4;j++){
        int f = w*32 + i2*16 + g*4 + j;
        float v = acc[i2][n2][j] + bias[f];
        int bi = nsafe*256 + f;
        v = v * (gg[bi] * BNI) + be[bi];
        v = tanh_f(v);
        if (MODE == 0) y_r[i2][n2][j] = v;
        if (MODE == 2){ v += y_r[i2][n2][j]; y_r[i2][n2][j] = v; }
        vv[j] = nok ? v : 0.f;
      }
      int fb2 = (w*32 + i2*16 + g*4)*2;
      uint2 u; u.x = pk2(vv[0], vv[1]); u.y = pk2(vv[2], vv[3]);
      *(uint2*)(ybf_c + n*512 + (fb2 ^ ((n & 15) << 4))) = u;
    }
  }
}

__global__ __launch_bounds__(512) void k_mega(const short* __restrict__ x_bf,
    const short* __restrict__ gc1wT, const short* __restrict__ wgT,
    const float* __restrict__ gc1_att, const float* __restrict__ gc1_b,
    const float* __restrict__ bn1_g, const float* __restrict__ bn1_b,
    const float* __restrict__ a1, const float* __restrict__ b1,
    const float* __restrict__ g1, const float* __restrict__ be1,
    const float* __restrict__ a2, const float* __restrict__ b2,
    const float* __restrict__ g2, const float* __restrict__ be2,
    const float* __restrict__ gc7_w, const float* __restrict__ gc7_att,
    const float* __restrict__ gc7_b, const float* __restrict__ x,
    const float* __restrict__ dct, float* __restrict__ out)
{
  __shared__ __align__(16) char ybf_c[40960];
  __shared__ __align__(16) char tT_c[65536];
  __shared__ __align__(16) char am_c[20480];
  __shared__ float xo_l[1320];
  __shared__ float dct_l[400];

  int b = blockIdx.x, tid = threadIdx.x;
  int w = tid >> 6, lane = tid & 63, fl = lane & 15, g = lane >> 4;

  for (int i = tid; i < 4096; i += 512) ((float4v*)tT_c)[i] = (float4v){0.f,0.f,0.f,0.f};
  for (int i = tid; i < 400; i += 512) dct_l[i] = dct[i];
  for (int i = tid; i < 320; i += 512){
    int m = i >> 2, kq = i & 3;
    short8 v = *(const short8*)&x_bf[(b*80 + m)*32 + kq*8];
    *(short8*)(ybf_c + m*512 + ((kq*16) ^ ((m & 15) << 4)));
    *(short8*)(ybf_c + m*512 + ((kq*16) ^ ((m & 15) << 4))) = v;
  }
  __syncthreads();

  float4v y_r[2][5];
  uint2 amu[4]; int amb[4];

  // ---- entry layer (gc1, K=32) ----
  #pragma unroll
  for (int s=0;s<4;s++){
    int i = tid + s*512;
    if (i < 1920) am_addr(i, gc1_att, &amu[s], &amb[s]); else amb[s] = -1;
  }
  do_g1<1>(gc1wT, 32, w, fl, g, ybf_c, tT_c);
  #pragma unroll
  for (int s=0;s<4;s++) if (amb[s] >= 0) *(uint2*)(am_c + amb[s]) = amu[s];
  __syncthreads();
  do_g2<0>(gc1_b, bn1_g, bn1_b, y_r, w, fl, g, tT_c, am_c, ybf_c);
  __syncthreads();

  for (int l = 0; l < 12; l++){
    #pragma unroll
    for (int s=0;s<4;s++){
      int i = tid + s*512;
      if (i < 1920) am_addr(i, a1 + l*4356, &amu[s], &amb[s]); else amb[s] = -1;
    }
    do_g1<8>(wgT + l*65536, 256, w, fl, g, ybf_c, tT_c);
    #pragma unroll
    for (int s=0;s<4;s++) if (amb[s] >= 0) *(uint2*)(am_c + amb[s]) = amu[s];
    __syncthreads();
    do_g2<1>(b1 + l*256, g1 + (long)l*16896, be1 + (long)l*16896, y_r, w, fl, g,
             tT_c, am_c, ybf_c);
    __syncthreads();
    #pragma unroll
    for (int s=0;s<4;s++){
      int i = tid + s*512;
      if (i < 1920) am_addr(i, a2 + l*4356, &amu[s], &amb[s]); else amb[s] = -1;
    }
    do_g1<8>(wgT + (12 + l)*65536, 256, w, fl, g, ybf_c, tT_c);
    #pragma unroll
    for (int s=0;s<4;s++) if (amb[s] >= 0) *(uint2*)(am_c + amb[s]) = amu[s];
    __syncthreads();
    do_g2<2>(b2 + l*256, g2 + (long)l*16896, be2 + (long)l*16896, y_r, w, fl, g,
             tT_c, am_c, ybf_c);
    __syncthreads();
  }

  // ---- gc7 tail ----
  // stage w7 [32 f][256 k] bf16 into am region (rows 512 B)
  for (int i = tid; i < 2048; i += 512){
    int f = i >> 6, kq = (i & 63)*4;
    float v0=0.f, v1=0.f, v2=0.f, v3=0.f;
    if (f < 20){
      v0 = gc7_w[(kq+0)*20 + f]; v1 = gc7_w[(kq+1)*20 + f];
      v2 = gc7_w[(kq+2)*20 + f]; v3 = gc7_w[(kq+3)*20 + f];
    }
    uint2 u; u.x = pk2(v0, v1); u.y = pk2(v2, v3);
    *(uint2*)(am_c + f*512 + ((kq*2) ^ ((f & 15) << 4))) = u;
  }
  __syncthreads();

  // G1t: t2 = y @ w7 (N=32, K=256), all waves redundant, w0 writes
  float4v at[5][2];
  #pragma unroll
  for (int i=0;i<5;i++){ at[i][0] = (float4v){0.f,0.f,0.f,0.f}; at[i][1] = (float4v){0.f,0.f,0.f,0.f}; }
  #pragma unroll
  for (int ks = 0; ks < 8; ks++){
    short8 bf[2];
    #pragma unroll
    for (int n=0;n<2;n++){
      int f = n*16 + fl;
      bf[n] = *(const short8*)(am_c + f*512 + (((ks*32 + g*8)*2) ^ ((f & 15) << 4)));
    }
    #pragma unroll
    for (int i=0;i<5;i++){
      int m = i*16 + fl;
      short8 af = *(const short8*)(ybf_c + m*512 + (((ks*32 + g*8)*2) ^ ((m & 15) << 4)));
      at[i][0] = __builtin_amdgcn_mfma_f32_16x16x32_bf16(af, bf[0], at[i][0], 0,0,0);
      at[i][1] = __builtin_amdgcn_mfma_f32_16x16x32_bf16(af, bf[1], at[i][1], 0,0,0);
    }
  }
  if (w == 0){
    #pragma unroll
    for (int i=0;i<5;i++){
      int mb = (i*16 + g*4)*2;
      #pragma unroll
      for (int n=0;n<2;n++){
        int f = n*16 + fl;
        uint2 u; u.x = pk2(at[i][n][0], at[i][n][1]); u.y = pk2(at[i][n][2], at[i][n][3]);
        *(uint2*)(tT_c + f*256 + (mb ^ ((f & 15) << 4))) = u;
      }
    }
  }
  __syncthreads();
  stage_Am(gc7_att, tid, am_c);
  __syncthreads();

  // G2't: out'[f32][n80] = t2_T @ A7^T, all waves redundant, w0 epilogue
  float4v a2t[2][5];
  #pragma unroll
  for (int i=0;i<2;i++)
    #pragma unroll
    for (int n=0;n<5;n++) a2t[i][n] = (float4v){0.f,0.f,0.f,0.f};
  #pragma unroll
  for (int ks = 0; ks < 3; ks++){
    short8 bA[5];
    #pragma unroll
    for (int n2=0;n2<5;n2++){
      int n = n2*16 + fl;
      bA[n2] = *(const short8*)(am_c + n*256 + (((ks*32 + g*8)*2) ^ ((n & 15) << 4)));
    }
    #pragma unroll
    for (int i2=0;i2<2;i2++){
      int f = i2*16 + fl;
      short8 af = *(const short8*)(tT_c + f*256 + (((ks*32 + g*8)*2) ^ ((f & 15) << 4)));
      #pragma unroll
      for (int n2=0;n2<5;n2++)
        a2t[i2][n2] = __builtin_amdgcn_mfma_f32_16x16x32_bf16(af, bA[n2], a2t[i2][n2], 0,0,0);
    }
  }
  if (w == 0){
    #pragma unroll
    for (int i2=0;i2<2;i2++){
      #pragma unroll
      for (int n2=0;n2<5;n2++){
        int n = n2*16 + fl;
        #pragma unroll
        for (int j=0;j<4;j++){
          int f = i2*16 + g*4 + j;
          if (f < 20 && n < 66)
            xo_l[n*20 + f] = a2t[i2][n2][j] + gc7_b[f] + x[(b*66 + n)*20 + f];
        }
      }
    }
  }
  __syncthreads();

  for (int idx = tid; idx < 1320; idx += 512){
    int r = idx / 66, fn = idx % 66;
    float s = 0.f;
    #pragma unroll
    for (int k = 0; k < 10; k++) s += dct_l[k*20 + r] * xo_l[fn*20 + k];
    out[(b*20 + r)*66 + fn] = s;
  }
}

extern "C" void kernel_launch(void* const* d_in, const int* in_sizes, int n_in,
                              void* d_out, int out_size, void* d_ws, size_t ws_size,
                              hipStream_t stream) {
  const float* src      = (const float*)d_in[0];
  const float* convQ_w1 = (const float*)d_in[1];
  const float* convQ_w2 = (const float*)d_in[2];
  const float* convK_w1 = (const float*)d_in[3];
  const float* convK_w2 = (const float*)d_in[4];
  const float* gc1_w    = (const float*)d_in[5];
  const float* gc1_att  = (const float*)d_in[6];
  const float* gc1_b    = (const float*)d_in[7];
  const float* bn1_g    = (const float*)d_in[8];
  const float* bn1_b    = (const float*)d_in[9];
  const float* gcb_w1   = (const float*)d_in[10];
  const float* gcb_att1 = (const float*)d_in[11];
  const float* gcb_b1   = (const float*)d_in[12];
  const float* gcb_bn1g = (const float*)d_in[13];
  const float* gcb_bn1b = (const float*)d_in[14];
  const float* gcb_w2   = (const float*)d_in[15];
  const float* gcb_att2 = (const float*)d_in[16];
  const float* gcb_b2   = (const float*)d_in[17];
  const float* gcb_bn2g = (const float*)d_in[18];
  const float* gcb_bn2b = (const float*)d_in[19];
  const float* gc7_w    = (const float*)d_in[20];
  const float* gc7_att  = (const float*)d_in[21];
  const float* gc7_b    = (const float*)d_in[22];
  float* out = (float*)d_out;

  float* ws    = (float*)d_ws;
  float* dct   = ws;
  float* x     = ws + 512;
  short* x_bf  = (short*)(ws + 169472);
  short* wgT   = (short*)(ws + 333312);
  short* gc1wT = (short*)(ws + 1119744);
  short* w1T   = (short*)(ws + 1123840);
  short* w2T   = (short*)(ws + 1254912);
  short* kc1q  = (short*)(ws + 1582592);
  float* key   = ws + 2237952;
  float* q     = ws + 3253760;
  float* att   = ws + 3286528;

  k_init_dct<<<1, 512, 0, stream>>>(dct);
  k_wconv1<<<1024, 256, 0, stream>>>(convK_w1, convQ_w1, w1T);
  k_wconv2<<<2560, 256, 0, stream>>>(convK_w2, convQ_w2, w2T);
  k_wgcn<<<6144, 256, 0, stream>>>(gcb_w1, gcb_w2, wgT);
  k_wgc1<<<32, 256, 0, stream>>>(gc1_w, gc1wT);

  k_conv1<<<dim3(128,4), 256, 0, stream>>>(src, w1T, kc1q);
  k_conv2<<<dim3(128,4), 256, 0, stream>>>(kc1q, w2T, key, q);
  k_att<<<128, 64, 0, stream>>>(q, key, att);
  k_build_x<<<128, 256, 0, stream>>>(src, att, dct, x, x_bf);

  k_mega<<<128, 512, 0, stream>>>(x_bf, gc1wT, wgT,
      gc1_att, gc1_b, bn1_g, bn1_b,
      gcb_att1, gcb_b1, gcb_bn1g, gcb_bn1b,
      gcb_att2, gcb_b2, gcb_bn2g, gcb_bn2b,
      gc7_w, gc7_att, gc7_b, x, dct, out);
}